// Round 4
// baseline (350.531 us; speedup 1.0000x reference)
//
#include <hip/hip_runtime.h>
#include <hip/hip_cooperative_groups.h>
#include <float.h>

namespace cg = cooperative_groups;

#define D_IN  128
#define D_OUT 32
#define H     512
#define W     512
#define W4    128            // W/4 float4 lanes per row
#define HB    8              // output H rows per tile
#define ZR    (HB + 8)       // staged rows incl. h-halo
#define NTHR  512
#define NTILE (D_OUT * (H / HB))   // 2048 tiles
#define NT    (D_OUT * H * W4)     // 2,097,152 float4 tasks

// ordered-uint encoding: monotone float -> uint32 for atomicMin/Max
__device__ __forceinline__ unsigned f2key(float f) {
    unsigned u = __float_as_uint(f);
    return (u & 0x80000000u) ? ~u : (u | 0x80000000u);
}
__device__ __forceinline__ float key2f(unsigned k) {
    unsigned u = (k & 0x80000000u) ? (k ^ 0x80000000u) : ~k;
    return __uint_as_float(u);
}

// One cooperative kernel: z-conv -> sync -> h+w conv (+min/max atomics)
// -> sync -> normalize. LDS 48 KiB -> 3 blocks/CU, grid sized for residency.
__global__ __launch_bounds__(NTHR)
void fused_all(const float* __restrict__ inp, float* __restrict__ bufA,
               float* __restrict__ bufB, float* __restrict__ out,
               const float* __restrict__ bxy_p, const float* __restrict__ bz_p,
               unsigned* __restrict__ fin_u) {
    cg::grid_group grid = cg::this_grid();
    __shared__ float zbuf[ZR * W];   // 32 KiB
    __shared__ float hbuf[HB * W];   // 16 KiB
    __shared__ float smin[8], smax[8];

    if (blockIdx.x == 0 && threadIdx.x == 0) {
        fin_u[0] = 0xFFFFFFFFu;      // running min key
        fin_u[1] = 0u;               // running max key
    }

    const float bz = bz_p[0], bx = bxy_p[0];
    const float iz = 1.0f / (2.0f * bz * bz);
    const float ix = 1.0f / (2.0f * bx * bx);
    float wz[9], wx[9];
#pragma unroll
    for (int k = 0; k < 9; ++k) {
        float dd = (float)(k - 4);
        wz[k] = expf(-dd * dd * iz);
        wx[k] = expf(-dd * dd * ix);
    }

    const float4* in4 = (const float4*)inp;
    float4* a4 = (float4*)bufA;
    float4* b4 = (float4*)bufB;
    float4* o4 = (float4*)out;
    float4* z4 = (float4*)zbuf;
    float4* h4 = (float4*)hbuf;

    const int gstr = gridDim.x * NTHR;

    // ---- P1: z-conv (stride 4, pad 3): inp -> bufA, pure streaming ----
    for (int t = blockIdx.x * NTHR + threadIdx.x; t < NT; t += gstr) {
        int base = t & 0xFFFF;       // h*W4 + w4 within a slice
        int d    = t >> 16;
        float4 acc = make_float4(0.f, 0.f, 0.f, 0.f);
#pragma unroll
        for (int k = 0; k < 9; ++k) {
            int din = 4 * d - 3 + k;
            if ((unsigned)din < D_IN) {
                float4 v = in4[din * (H * W4) + base];
                acc.x += v.x * wz[k]; acc.y += v.y * wz[k];
                acc.z += v.z * wz[k]; acc.w += v.w * wz[k];
            }
        }
        a4[t] = acc;
    }
    grid.sync();

    // ---- P2: h-conv + w-conv per (d, 8-row) tile, fused min/max ----
    float lmin = FLT_MAX, lmax = -FLT_MAX;
    for (int tile = blockIdx.x; tile < NTILE; tile += gridDim.x) {
        const int d  = tile >> 6;
        const int h0 = (tile & 63) * HB;
        // stage rows [h0-4, h0+12) from bufA (zero-pad outside H)
#pragma unroll
        for (int i = 0; i < (ZR * W4) / NTHR; ++i) {
            int t = threadIdx.x + i * NTHR;
            int r = t >> 7, c4 = t & (W4 - 1);
            int h = h0 - 4 + r;
            z4[t] = ((unsigned)h < H) ? a4[(d * H + h) * W4 + c4]
                                      : make_float4(0.f, 0.f, 0.f, 0.f);
        }
        __syncthreads();
        // h-conv zbuf -> hbuf
#pragma unroll
        for (int i = 0; i < (HB * W4) / NTHR; ++i) {
            int t = threadIdx.x + i * NTHR;
            int r = t >> 7, c4 = t & (W4 - 1);
            float4 acc = make_float4(0.f, 0.f, 0.f, 0.f);
#pragma unroll
            for (int k = 0; k < 9; ++k) {
                float4 v = z4[(r + k) * W4 + c4];
                acc.x += v.x * wx[k]; acc.y += v.y * wx[k];
                acc.z += v.z * wx[k]; acc.w += v.w * wx[k];
            }
            h4[t] = acc;
        }
        __syncthreads();
        // w-conv hbuf -> bufB (+ local min/max). Next tile's staging only
        // touches zbuf, h-conv(t+1) is gated by the first barrier -> 2
        // barriers per tile suffice.
#pragma unroll
        for (int i = 0; i < (HB * W4) / NTHR; ++i) {
            int t = threadIdx.x + i * NTHR;
            int r = t >> 7, c4 = t & (W4 - 1);
            float4 zv = make_float4(0.f, 0.f, 0.f, 0.f);
            float4 va = (c4 > 0)      ? h4[r * W4 + c4 - 1] : zv;
            float4 vb =                 h4[r * W4 + c4];
            float4 vc = (c4 < W4 - 1) ? h4[r * W4 + c4 + 1] : zv;
            float win[12] = {va.x, va.y, va.z, va.w,
                             vb.x, vb.y, vb.z, vb.w,
                             vc.x, vc.y, vc.z, vc.w};
            float4 o = make_float4(0.f, 0.f, 0.f, 0.f);
#pragma unroll
            for (int k = 0; k < 9; ++k) {
                o.x += win[k]     * wx[k];
                o.y += win[k + 1] * wx[k];
                o.z += win[k + 2] * wx[k];
                o.w += win[k + 3] * wx[k];
            }
            b4[(d * H + h0 + r) * W4 + c4] = o;
            lmin = fminf(lmin, fminf(fminf(o.x, o.y), fminf(o.z, o.w)));
            lmax = fmaxf(lmax, fmaxf(fmaxf(o.x, o.y), fmaxf(o.z, o.w)));
        }
        __syncthreads();
    }

    // block reduce -> 2 device atomics (order-independent => deterministic)
#pragma unroll
    for (int off = 32; off > 0; off >>= 1) {
        lmin = fminf(lmin, __shfl_down(lmin, off, 64));
        lmax = fmaxf(lmax, __shfl_down(lmax, off, 64));
    }
    int lane = threadIdx.x & 63, wv = threadIdx.x >> 6;
    if (lane == 0) { smin[wv] = lmin; smax[wv] = lmax; }
    __syncthreads();
    if (threadIdx.x == 0) {
        float mn = smin[0], mx = smax[0];
#pragma unroll
        for (int i = 1; i < 8; ++i) { mn = fminf(mn, smin[i]); mx = fmaxf(mx, smax[i]); }
        atomicMin(&fin_u[0], f2key(mn));
        atomicMax(&fin_u[1], f2key(mx));
    }
    grid.sync();

    // ---- P3: normalize (bufB is LLC-warm) ----
    float mn  = key2f(fin_u[0]);
    float inv = 1.0f / (key2f(fin_u[1]) - mn);
    for (int t = blockIdx.x * NTHR + threadIdx.x; t < NT; t += gstr) {
        float4 v = b4[t];
        o4[t] = make_float4((v.x - mn) * inv, (v.y - mn) * inv,
                            (v.z - mn) * inv, (v.w - mn) * inv);
    }
}

extern "C" void kernel_launch(void* const* d_in, const int* in_sizes, int n_in,
                              void* d_out, int out_size, void* d_ws, size_t ws_size,
                              hipStream_t stream) {
    const float* inp    = (const float*)d_in[0];
    // mu_z / sig_z produce a positive global scale that cancels in min-max norm.
    const float* bet_xy = (const float*)d_in[3];
    const float* bet_z  = (const float*)d_in[4];
    float* out = (float*)d_out;

    char* ws = (char*)d_ws;
    unsigned* fin_u = (unsigned*)ws;                         // 2 encoded uints
    float* bufA = (float*)(ws + 65536);                      // 32 MiB z-conv out
    float* bufB = (float*)(ws + 65536 + (size_t)33554432);   // 32 MiB hw-conv out

    // Co-residency sizing, computed once (same value every call).
    static int grid_blocks = [] {
        int per_cu = 0;
        hipOccupancyMaxActiveBlocksPerMultiprocessor(&per_cu, fused_all, NTHR, 0);
        if (per_cu < 1) per_cu = 1;
        hipDeviceProp_t p;
        int cus = 256;
        if (hipGetDeviceProperties(&p, 0) == hipSuccess) cus = p.multiProcessorCount;
        int g = per_cu * cus;
        return g > NTILE ? NTILE : g;
    }();

    void* args[] = {(void*)&inp, (void*)&bufA, (void*)&bufB, (void*)&out,
                    (void*)&bet_xy, (void*)&bet_z, (void*)&fin_u};
    hipLaunchCooperativeKernel((const void*)fused_all, dim3(grid_blocks), dim3(NTHR),
                               args, 0, stream);
}

// Round 5
// 262.695 us; speedup vs baseline: 1.3344x; 1.3344x over previous
//
#include <hip/hip_runtime.h>
#include <float.h>

#define D_IN  128
#define D_OUT 32
#define H     512
#define W     512
#define W4    128            // W/4 float4 lanes per row
#define HB    8              // output H rows per block
#define ZR    (HB + 8)       // z-conv rows incl. h-halo (16)
#define NTHR  512
#define NTILE (D_OUT * (H / HB))   // 2048 blocks

// ordered-uint encoding: monotone float -> uint32 for atomicMin/Max
__device__ __forceinline__ unsigned f2key(float f) {
    unsigned u = __float_as_uint(f);
    return (u & 0x80000000u) ? ~u : (u | 0x80000000u);
}
__device__ __forceinline__ float key2f(unsigned k) {
    unsigned u = (k & 0x80000000u) ? (k ^ 0x80000000u) : ~k;
    return __uint_as_float(u);
}

// Fused separable conv z(stride4,pad3) -> h(pad4) -> w(pad4), one block per
// (d, 8-row tile). LDS 48 KiB -> 3 blocks/CU (24 waves). Min/max via 2
// device atomics per block (order-independent => deterministic).
__global__ __launch_bounds__(NTHR)
void conv3d_fused(const float* __restrict__ inp, float* __restrict__ out,
                  const float* __restrict__ bxy_p, const float* __restrict__ bz_p,
                  unsigned* __restrict__ fin_u) {
    __shared__ float zbuf[ZR * W];   // 32 KiB
    __shared__ float hbuf[HB * W];   // 16 KiB
    __shared__ float smin[8], smax[8];

    const int d  = blockIdx.x >> 6;          // 64 h-tiles per output slice
    const int h0 = (blockIdx.x & 63) * HB;

    const float bz = bz_p[0], bx = bxy_p[0];
    const float iz = 1.0f / (2.0f * bz * bz);
    const float ix = 1.0f / (2.0f * bx * bx);
    float wz[9], wx[9];
#pragma unroll
    for (int k = 0; k < 9; ++k) {
        float dd = (float)(k - 4);
        wz[k] = expf(-dd * dd * iz);
        wx[k] = expf(-dd * dd * ix);
    }

    const float4* in4 = (const float4*)inp;
    float4* z4 = (float4*)zbuf;
    float4* h4 = (float4*)hbuf;

    // ---- Phase A: z-conv (stride 4, pad 3) rows [h0-4, h0+12) -> zbuf ----
#pragma unroll
    for (int i = 0; i < (ZR * W4) / NTHR; ++i) {
        int t  = threadIdx.x + i * NTHR;
        int r  = t >> 7;                  // 0..15
        int c4 = t & (W4 - 1);
        int h  = h0 - 4 + r;
        float4 acc = make_float4(0.f, 0.f, 0.f, 0.f);
        if ((unsigned)h < H) {
            int base = h * W4 + c4;
#pragma unroll
            for (int k = 0; k < 9; ++k) {
                int din = 4 * d - 3 + k;
                if ((unsigned)din < D_IN) {
                    float4 v = in4[din * (H * W4) + base];
                    acc.x += v.x * wz[k]; acc.y += v.y * wz[k];
                    acc.z += v.z * wz[k]; acc.w += v.w * wz[k];
                }
            }
        }
        z4[t] = acc;
    }
    __syncthreads();

    // ---- Phase B: h-conv (pad 4) zbuf -> hbuf ----
#pragma unroll
    for (int i = 0; i < (HB * W4) / NTHR; ++i) {
        int t  = threadIdx.x + i * NTHR;
        int r  = t >> 7;
        int c4 = t & (W4 - 1);
        float4 acc = make_float4(0.f, 0.f, 0.f, 0.f);
#pragma unroll
        for (int k = 0; k < 9; ++k) {
            float4 v = z4[(r + k) * W4 + c4];
            acc.x += v.x * wx[k]; acc.y += v.y * wx[k];
            acc.z += v.z * wx[k]; acc.w += v.w * wx[k];
        }
        h4[t] = acc;
    }
    __syncthreads();

    // ---- Phase C: w-conv (pad 4) hbuf -> global + min/max ----
    float lmin = FLT_MAX, lmax = -FLT_MAX;
    float4* out4 = (float4*)out;
#pragma unroll
    for (int i = 0; i < (HB * W4) / NTHR; ++i) {
        int t  = threadIdx.x + i * NTHR;
        int r  = t >> 7;
        int c4 = t & (W4 - 1);
        float4 zv = make_float4(0.f, 0.f, 0.f, 0.f);
        float4 va = (c4 > 0)      ? h4[r * W4 + c4 - 1] : zv;
        float4 vb =                 h4[r * W4 + c4];
        float4 vc = (c4 < W4 - 1) ? h4[r * W4 + c4 + 1] : zv;
        float win[12] = {va.x, va.y, va.z, va.w,
                         vb.x, vb.y, vb.z, vb.w,
                         vc.x, vc.y, vc.z, vc.w};
        float4 o = make_float4(0.f, 0.f, 0.f, 0.f);
#pragma unroll
        for (int k = 0; k < 9; ++k) {
            o.x += win[k]     * wx[k];
            o.y += win[k + 1] * wx[k];
            o.z += win[k + 2] * wx[k];
            o.w += win[k + 3] * wx[k];
        }
        out4[(d * H + h0 + r) * W4 + c4] = o;
        lmin = fminf(lmin, fminf(fminf(o.x, o.y), fminf(o.z, o.w)));
        lmax = fmaxf(lmax, fmaxf(fmaxf(o.x, o.y), fmaxf(o.z, o.w)));
    }

    // block reduce -> 2 atomics
#pragma unroll
    for (int off = 32; off > 0; off >>= 1) {
        lmin = fminf(lmin, __shfl_down(lmin, off, 64));
        lmax = fmaxf(lmax, __shfl_down(lmax, off, 64));
    }
    int lane = threadIdx.x & 63, wv = threadIdx.x >> 6;
    if (lane == 0) { smin[wv] = lmin; smax[wv] = lmax; }
    __syncthreads();
    if (threadIdx.x == 0) {
        float mn = smin[0], mx = smax[0];
#pragma unroll
        for (int i = 1; i < 8; ++i) { mn = fminf(mn, smin[i]); mx = fmaxf(mx, smax[i]); }
        atomicMin(&fin_u[0], f2key(mn));
        atomicMax(&fin_u[1], f2key(mx));
    }
}

// Normalize.
__global__ void norm_kernel(const float* __restrict__ in, float* __restrict__ out,
                            const unsigned* __restrict__ fin_u) {
    int tid = blockIdx.x * blockDim.x + threadIdx.x;
    float mn  = key2f(fin_u[0]);
    float inv = 1.0f / (key2f(fin_u[1]) - mn);
    float4 v = ((const float4*)in)[tid];
    ((float4*)out)[tid] = make_float4((v.x - mn) * inv, (v.y - mn) * inv,
                                      (v.z - mn) * inv, (v.w - mn) * inv);
}

extern "C" void kernel_launch(void* const* d_in, const int* in_sizes, int n_in,
                              void* d_out, int out_size, void* d_ws, size_t ws_size,
                              hipStream_t stream) {
    const float* inp    = (const float*)d_in[0];
    // mu_z / sig_z produce a positive global scale that cancels in min-max norm.
    const float* bet_xy = (const float*)d_in[3];
    const float* bet_z  = (const float*)d_in[4];
    float* out = (float*)d_out;

    char* ws = (char*)d_ws;
    unsigned* fin_u = (unsigned*)ws;             // [0]=min key, [1]=max key
    float* bufB = (float*)(ws + 65536);          // 32 MiB conv output

    // init atomic slots: min key = 0xFFFFFFFF, max key = 0x00000000
    hipMemsetAsync(&fin_u[0], 0xFF, 4, stream);
    hipMemsetAsync(&fin_u[1], 0x00, 4, stream);

    conv3d_fused<<<NTILE, NTHR, 0, stream>>>(inp, bufB, bet_xy, bet_z, fin_u);

    const int NTASK = D_OUT * H * W4;            // 2,097,152 float4
    norm_kernel<<<NTASK / 256, 256, 0, stream>>>(bufB, out, fin_u);
}